// Round 1
// baseline (1061.267 us; speedup 1.0000x reference)
//
#include <hip/hip_runtime.h>
#include <stdint.h>

// PCT forward: stem(conv1x1+BN+ReLU ×2) -> concat cls -> 4× [LN,QKV,attn,fc,LN,FF]
// B=8 C=256 N=1024 D=256 DK=16 DV=32 H=8 NB=4 P=1025, M_tok=8200
// Strategy: bf16 MFMA NT-GEMMs (16x16x32), flash attention with 32x32x16 MFMA,
// residual h kept f32 in d_out. Weights converted to bf16 in d_ws each call.

typedef unsigned short u16;
typedef unsigned int   u32;
typedef __bf16 bf16x8 __attribute__((ext_vector_type(8)));
typedef float  f32x4  __attribute__((ext_vector_type(4)));
typedef float  f32x16 __attribute__((ext_vector_type(16)));

#define DEV static __device__ __forceinline__

DEV float b2f(u16 h){ u32 u = ((u32)h) << 16; return __builtin_bit_cast(float, u); }
DEV u16 f2b(float f){ u32 u = __builtin_bit_cast(u32, f); u32 r = (u + 0x7fffu + ((u >> 16) & 1u)) >> 16; return (u16)r; }
DEV float gelu_f(float x){ return 0.5f * x * (1.0f + erff(x * 0.7071067811865475f)); }

typedef void __attribute__((address_space(1)))* gas_t;
typedef void __attribute__((address_space(3)))* las_t;
DEV void cp16(const void* g, void* l){
  __builtin_amdgcn_global_load_lds((gas_t)(uintptr_t)g, (las_t)(uintptr_t)l, 16, 0, 0);
}

// ---------------- weight conversion f32 -> bf16 (with QKV concat) ----------------
struct Seg { const float* src; u16* dst; int n; int period; int dstride; int block0; };
struct SegPack { Seg s[8]; };

__global__ __launch_bounds__(256) void k_convert(SegPack p){
  int bid = blockIdx.x;
  int si = 0;
  #pragma unroll
  for (int i = 1; i < 8; i++) if (bid >= p.s[i].block0) si = i;
  const Seg sg = p.s[si];
  int e0 = (bid - sg.block0) * 2048 + threadIdx.x * 8;
  #pragma unroll
  for (int k = 0; k < 8; k++){
    int e = e0 + k;
    if (e < sg.n) sg.dst[(e / sg.period) * sg.dstride + (e % sg.period)] = f2b(sg.src[e]);
  }
}

// ---------------- x [B,C,N] f32 -> xT [B,N,C] bf16 ----------------
__global__ __launch_bounds__(256) void k_transpose_x(const float* __restrict__ x, u16* __restrict__ xT){
  __shared__ float t[32][33];
  int b = blockIdx.z, ct = blockIdx.y, nt = blockIdx.x;
  int tx = threadIdx.x & 31, ty = threadIdx.x >> 5;  // ty 0..7
  const float* xp = x + ((size_t)b * 256 + ct * 32) * 1024 + nt * 32;
  #pragma unroll
  for (int k = 0; k < 4; k++) t[ty + 8*k][tx] = xp[(size_t)(ty + 8*k) * 1024 + tx];
  __syncthreads();
  u16* op = xT + ((size_t)b * 1024 + nt * 32) * 256 + ct * 32;
  #pragma unroll
  for (int k = 0; k < 4; k++) op[(size_t)(ty + 8*k) * 256 + tx] = f2b(t[tx][ty + 8*k]);
}

// ---------------- cls token row ----------------
__global__ void k_cls(const float* __restrict__ cls, float* __restrict__ h){
  int d = threadIdx.x;
  #pragma unroll
  for (int b = 0; b < 8; b++) h[(size_t)b * 1025 * 256 + d] = cls[d];
}

// ---------------- LayerNorm: h f32 -> y bf16 (wave per token) ----------------
__global__ __launch_bounds__(256) void k_ln(const float* __restrict__ h, const float* __restrict__ g,
                                            const float* __restrict__ bt, u16* __restrict__ y){
  int lane = threadIdx.x & 63, wv = threadIdx.x >> 6;
  long t = (long)blockIdx.x * 4 + wv;
  if (t >= 8200) return;
  const float* row = h + t * 256;
  float4 v = *reinterpret_cast<const float4*>(row + lane * 4);
  float s = v.x + v.y + v.z + v.w;
  float q = v.x*v.x + v.y*v.y + v.z*v.z + v.w*v.w;
  #pragma unroll
  for (int o = 32; o > 0; o >>= 1){ s += __shfl_xor(s, o); q += __shfl_xor(q, o); }
  float mean = s * (1.f/256.f);
  float var  = q * (1.f/256.f) - mean * mean;
  float rs = rsqrtf(var + 1e-5f);
  ushort4 ov;
  const float* vp = &v.x;
  u16* o16 = (u16*)&ov;
  #pragma unroll
  for (int j = 0; j < 4; j++){
    int c = lane * 4 + j;
    o16[j] = f2b((vp[j] - mean) * rs * g[c] + bt[c]);
  }
  *reinterpret_cast<ushort4*>(y + t * 256 + lane * 4) = ov;
}

// ---------------- NT GEMM: out[m,e] = sum_k A[m,k]*W[e,k], bf16 in, f32 acc ----------------
// 128x128 tile, BK=64, 4 waves (2x2), XOR-swizzled linear LDS + global_load_lds w=16.
// EPI: 0 bf16 store | 1 bn+relu->bf16 | 2 bn+relu->f32 row-shifted (stem2) |
//      3 f32 += | 4 (+bias,gelu)->bf16 | 5 f32 += (+bias)
template<int EPI>
__global__ __launch_bounds__(256) void k_gemm(const u16* __restrict__ A, const u16* __restrict__ W,
    int M, int K, int E, float* __restrict__ outF, u16* __restrict__ outB,
    const float* __restrict__ a0, const float* __restrict__ a1,
    const float* __restrict__ a2, const float* __restrict__ a3){
  __shared__ __align__(16) u16 As[8192];
  __shared__ __align__(16) u16 Bs[8192];
  const int tid = threadIdx.x;
  const int lane = tid & 63, wv = tid >> 6;
  const int wr = wv >> 1, wc = wv & 1;
  const int tM = blockIdx.x * 128, tN = blockIdx.y * 128;
  f32x4 acc[4][4];
  #pragma unroll
  for (int m = 0; m < 4; m++)
    #pragma unroll
    for (int n = 0; n < 4; n++)
      #pragma unroll
      for (int j = 0; j < 4; j++) acc[m][n][j] = 0.f;

  const int l8 = lane >> 3, lm = lane & 7;
  for (int k0 = 0; k0 < K; k0 += 64){
    __syncthreads();
    #pragma unroll
    for (int is = 0; is < 4; is++){
      int row = is * 32 + wv * 8 + l8;
      int kg = lm ^ (row & 7);                 // pre-swizzled source -> linear LDS
      int ra = tM + row; ra = ra < M ? ra : M - 1;
      cp16(A + (size_t)ra * K + k0 + kg * 8, As + is * 2048 + wv * 512);
      cp16(W + (size_t)(tN + row) * K + k0 + kg * 8, Bs + is * 2048 + wv * 512);
    }
    __syncthreads();
    #pragma unroll
    for (int kk = 0; kk < 2; kk++){
      bf16x8 af[4], bfv[4];
      #pragma unroll
      for (int m = 0; m < 4; m++){
        int row = wr * 64 + m * 16 + (lane & 15);
        int kg = (kk * 4 + (lane >> 4)) ^ (row & 7);
        af[m] = *reinterpret_cast<const bf16x8*>(&As[row * 64 + kg * 8]);
      }
      #pragma unroll
      for (int n = 0; n < 4; n++){
        int row = wc * 64 + n * 16 + (lane & 15);
        int kg = (kk * 4 + (lane >> 4)) ^ (row & 7);
        bfv[n] = *reinterpret_cast<const bf16x8*>(&Bs[row * 64 + kg * 8]);
      }
      #pragma unroll
      for (int m = 0; m < 4; m++)
        #pragma unroll
        for (int n = 0; n < 4; n++)
          acc[m][n] = __builtin_amdgcn_mfma_f32_16x16x32_bf16(af[m], bfv[n], acc[m][n], 0, 0, 0);
    }
  }
  // epilogue: D row=(lane>>4)*4+j, col=lane&15
  #pragma unroll
  for (int n = 0; n < 4; n++){
    const int col = tN + wc * 64 + n * 16 + (lane & 15);
    float scale = 0.f, shift = 0.f, bias = 0.f;
    if (EPI == 1 || EPI == 2){
      float gv = a0[col], bv = a1[col], mv = a2[col], vv = a3[col];
      scale = gv * rsqrtf(vv + 1e-5f);
      shift = bv - mv * scale;
    }
    if (EPI == 4 || EPI == 5) bias = a0[col];
    #pragma unroll
    for (int m = 0; m < 4; m++){
      const int row0 = tM + wr * 64 + m * 16 + ((lane >> 4) << 2);
      #pragma unroll
      for (int j = 0; j < 4; j++){
        int r = row0 + j;
        if (r < M){
          float v = acc[m][n][j];
          if (EPI == 0){ outB[(size_t)r * E + col] = f2b(v); }
          else if (EPI == 1){ v = v * scale + shift; v = v > 0.f ? v : 0.f; outB[(size_t)r * E + col] = f2b(v); }
          else if (EPI == 2){ v = v * scale + shift; v = v > 0.f ? v : 0.f; outF[(size_t)(r + (r >> 10) + 1) * 256 + col] = v; }
          else if (EPI == 3){ outF[(size_t)r * E + col] += v; }
          else if (EPI == 4){ outB[(size_t)r * E + col] = f2b(gelu_f(v + bias)); }
          else { outF[(size_t)r * E + col] += v + bias; }
        }
      }
    }
  }
}

// ---------------- attention: per (b,h,qtile128); 4 waves x 32 q-rows; JT=64 ----------------
// qkv [8200,512] bf16: q at col 0+h*16, k at 128+h*16, v at 256+h*32.
// softmax_with_policy: e=exp(s-m)*ap (ap=1 on diag, policy[j] off-diag, 0 for j>=P),
// out = (e+eps/n)/(sum+eps) => O = (sum e*v + eps/n * sum v) / (sum e + eps)
__global__ __launch_bounds__(256) void k_attn(const u16* __restrict__ qkv,
    const float* __restrict__ pol, u16* __restrict__ o){
  __shared__ __align__(16) u16 kl[64 * 24];        // [64 j][16 dk + 8 pad]
  __shared__ __align__(16) u16 vT[32 * 72];        // [32 dv][64 j + 8 pad]
  __shared__ __align__(16) u16 pl[4][32 * 72];     // per-wave P [32 q][64 j + 8 pad]
  __shared__ float vps[64][33];
  __shared__ float vsum[32];
  const int tid = threadIdx.x;
  const int lane = tid & 63, wv = tid >> 6;
  const int l32 = lane & 31, lh = lane >> 5;
  const int bid = blockIdx.x;
  const int bh = bid / 9, qt = bid - bh * 9;
  const int b = bh >> 3, hh = bh & 7;
  const size_t rowbase = (size_t)b * 1025;
  const int qrow0 = qt * 128 + wv * 32;
  int qr = qrow0 + l32; if (qr > 1024) qr = 1024;
  const bf16x8 qf = *reinterpret_cast<const bf16x8*>(qkv + (rowbase + qr) * 512 + hh * 16 + lh * 8);

  float mr[16], ls[16];
  f32x16 oacc;
  #pragma unroll
  for (int r = 0; r < 16; r++){ mr[r] = -3.0e38f; ls[r] = 0.f; oacc[r] = 0.f; }
  float vpart[8] = {0,0,0,0,0,0,0,0};
  const float* pb_ = pol + rowbase;
  const int sj = tid >> 2, sc = tid & 3;           // staging: j row 0..63, quarter 0..3

  for (int jt = 0; jt < 17; jt++){
    const int jb = jt * 64;
    __syncthreads();
    {
      int jg = jb + sj; bool jvld = jg <= 1024; int jc = jvld ? jg : 1024;
      ushort4 kd = *reinterpret_cast<const ushort4*>(qkv + (rowbase + jc) * 512 + 128 + hh * 16 + sc * 4);
      *reinterpret_cast<ushort4*>(&kl[sj * 24 + sc * 4]) = kd;
      bf16x8 vd = *reinterpret_cast<const bf16x8*>(qkv + (rowbase + jc) * 512 + 256 + hh * 32 + sc * 8);
      const u16* vdu = reinterpret_cast<const u16*>(&vd);
      #pragma unroll
      for (int q = 0; q < 8; q++){
        u16 val = jvld ? vdu[q] : (u16)0;
        vT[(sc * 8 + q) * 72 + sj] = val;
        vpart[q] += b2f(val);
      }
    }
    __syncthreads();
    bf16x8 kf0 = *reinterpret_cast<const bf16x8*>(&kl[l32 * 24 + lh * 8]);
    bf16x8 kf1 = *reinterpret_cast<const bf16x8*>(&kl[(l32 + 32) * 24 + lh * 8]);
    f32x16 fz;
    #pragma unroll
    for (int r = 0; r < 16; r++) fz[r] = 0.f;
    f32x16 s0 = __builtin_amdgcn_mfma_f32_32x32x16_bf16(qf, kf0, fz, 0, 0, 0);
    f32x16 s1 = __builtin_amdgcn_mfma_f32_32x32x16_bf16(qf, kf1, fz, 0, 0, 0);
    const int j0 = jb + l32, j1 = jb + 32 + l32;
    const bool v0 = j0 <= 1024, v1 = j1 <= 1024;
    const float pj0 = v0 ? pb_[j0] : 0.f;
    const float pj1 = v1 ? pb_[j1] : 0.f;
    #pragma unroll
    for (int r = 0; r < 16; r++){
      float sv0 = v0 ? s0[r] * 0.25f : -3.0e38f;
      float sv1 = v1 ? s1[r] * 0.25f : -3.0e38f;
      float mx = sv0 > sv1 ? sv0 : sv1;
      #pragma unroll
      for (int d2 = 1; d2 < 32; d2 <<= 1){ float t2 = __shfl_xor(mx, d2); mx = mx > t2 ? mx : t2; }
      float mn = mr[r] > mx ? mr[r] : mx;
      float corr = __expf(mr[r] - mn);
      mr[r] = mn;
      const int qrow = qrow0 + (r & 3) + 8 * (r >> 2) + 4 * lh;
      float ap0 = (qrow == j0) ? 1.f : pj0;
      float ap1 = (qrow == j1) ? 1.f : pj1;
      float e0 = v0 ? __expf(sv0 - mn) * ap0 : 0.f;
      float e1 = v1 ? __expf(sv1 - mn) * ap1 : 0.f;
      float rs2 = e0 + e1;
      #pragma unroll
      for (int d2 = 1; d2 < 32; d2 <<= 1) rs2 += __shfl_xor(rs2, d2);
      ls[r] = ls[r] * corr + rs2;
      oacc[r] *= corr;
      const int rm = (r & 3) + 8 * (r >> 2) + 4 * lh;
      pl[wv][rm * 72 + l32] = f2b(e0);
      pl[wv][rm * 72 + 32 + l32] = f2b(e1);
    }
    #pragma unroll
    for (int kc = 0; kc < 4; kc++){
      bf16x8 pa = *reinterpret_cast<const bf16x8*>(&pl[wv][l32 * 72 + kc * 16 + lh * 8]);
      bf16x8 vb = *reinterpret_cast<const bf16x8*>(&vT[l32 * 72 + kc * 16 + lh * 8]);
      oacc = __builtin_amdgcn_mfma_f32_32x32x16_bf16(pa, vb, oacc, 0, 0, 0);
    }
  }
  __syncthreads();
  #pragma unroll
  for (int q = 0; q < 8; q++) vps[sj][sc * 8 + q] = vpart[q];
  __syncthreads();
  if (tid < 32){
    float s2 = 0.f;
    for (int jj = 0; jj < 64; jj++) s2 += vps[jj][tid];
    vsum[tid] = s2;
  }
  __syncthreads();
  const float vsc = vsum[l32];
  #pragma unroll
  for (int r = 0; r < 16; r++){
    const int qrow = qrow0 + (r & 3) + 8 * (r >> 2) + 4 * lh;
    if (qrow <= 1024){
      float val = (oacc[r] + (1e-6f / 1025.f) * vsc) / (ls[r] + 1e-6f);
      o[(rowbase + qrow) * 256 + hh * 32 + l32] = f2b(val);
    }
  }
}

// ---------------- host ----------------
extern "C" void kernel_launch(void* const* d_in, const int* in_sizes, int n_in,
                              void* d_out, int out_size, void* d_ws, size_t ws_size,
                              hipStream_t stream){
  const float* x    = (const float*)d_in[0];
  const float* pol  = (const float*)d_in[1];
  const float* c1w  = (const float*)d_in[2];
  const float* c2w  = (const float*)d_in[3];
  const float* bn1g = (const float*)d_in[4];
  const float* bn1b = (const float*)d_in[5];
  const float* bn1m = (const float*)d_in[6];
  const float* bn1v = (const float*)d_in[7];
  const float* bn2g = (const float*)d_in[8];
  const float* bn2b = (const float*)d_in[9];
  const float* bn2m = (const float*)d_in[10];
  const float* bn2v = (const float*)d_in[11];
  const float* cls  = (const float*)d_in[12];
  const float* ln1g = (const float*)d_in[13];
  const float* ln1b = (const float*)d_in[14];
  const float* ln2g = (const float*)d_in[15];
  const float* ln2b = (const float*)d_in[16];
  const float* wq   = (const float*)d_in[17];
  const float* wk   = (const float*)d_in[18];
  const float* wvp  = (const float*)d_in[19];
  const float* fcw  = (const float*)d_in[20];
  const float* ffw1 = (const float*)d_in[21];
  const float* ffb1 = (const float*)d_in[22];
  const float* ffw2 = (const float*)d_in[23];
  const float* ffb2 = (const float*)d_in[24];
  float* h = (float*)d_out;

  u16* ws   = (u16*)d_ws;                    // needs ~30 MB of ws
  u16* wc1  = ws;                            // 65536
  u16* wc2  = wc1  + 65536;                  // 65536
  u16* wqkv = wc2  + 65536;                  // 4 x [512,256] = 524288
  u16* wfc  = wqkv + 524288;                 // 262144
  u16* wff1 = wfc  + 262144;                 // 524288
  u16* wff2 = wff1 + 524288;                 // 524288
  u16* xT   = wff2 + 524288;                 // 2097152
  u16* h1   = xT   + 2097152;                // 2097152
  u16* yb   = h1   + 2097152;                // 2099200
  u16* qkvb = yb   + 2099200;                // 4198400
  u16* ob   = qkvb + 4198400;                // 2099200
  u16* ub   = qkvb;                          // alias: qkv dead after attention

  SegPack sp;
  int b0 = 0;
  sp.s[0] = Seg{ c1w,  wc1,          65536,  65536,  0,      b0 }; b0 += 32;
  sp.s[1] = Seg{ c2w,  wc2,          65536,  65536,  0,      b0 }; b0 += 32;
  sp.s[2] = Seg{ wq,   wqkv,         131072, 32768,  131072, b0 }; b0 += 64;
  sp.s[3] = Seg{ wk,   wqkv + 32768, 131072, 32768,  131072, b0 }; b0 += 64;
  sp.s[4] = Seg{ wvp,  wqkv + 65536, 262144, 65536,  131072, b0 }; b0 += 128;
  sp.s[5] = Seg{ fcw,  wfc,          262144, 262144, 0,      b0 }; b0 += 128;
  sp.s[6] = Seg{ ffw1, wff1,         524288, 524288, 0,      b0 }; b0 += 256;
  sp.s[7] = Seg{ ffw2, wff2,         524288, 524288, 0,      b0 }; b0 += 256;

  k_convert<<<b0, 256, 0, stream>>>(sp);
  k_transpose_x<<<dim3(32, 8, 8), 256, 0, stream>>>(x, xT);
  k_cls<<<1, 256, 0, stream>>>(cls, h);
  k_gemm<1><<<dim3(64, 2), 256, 0, stream>>>(xT, wc1, 8192, 256, 256, nullptr, h1, bn1g, bn1b, bn1m, bn1v);
  k_gemm<2><<<dim3(64, 2), 256, 0, stream>>>(h1, wc2, 8192, 256, 256, h, nullptr, bn2g, bn2b, bn2m, bn2v);
  for (int i = 0; i < 4; i++){
    k_ln<<<2050, 256, 0, stream>>>(h, ln1g + i*256, ln1b + i*256, yb);
    k_gemm<0><<<dim3(65, 4), 256, 0, stream>>>(yb, wqkv + i*131072, 8200, 256, 512, nullptr, qkvb,
                                               nullptr, nullptr, nullptr, nullptr);
    k_attn<<<576, 256, 0, stream>>>(qkvb, pol, ob);
    k_gemm<3><<<dim3(65, 2), 256, 0, stream>>>(ob, wfc + i*65536, 8200, 256, 256, h, nullptr,
                                               nullptr, nullptr, nullptr, nullptr);
    k_ln<<<2050, 256, 0, stream>>>(h, ln2g + i*256, ln2b + i*256, yb);
    k_gemm<4><<<dim3(65, 4), 256, 0, stream>>>(yb, wff1 + i*131072, 8200, 256, 512, nullptr, ub,
                                               ffb1 + i*512, nullptr, nullptr, nullptr);
    k_gemm<5><<<dim3(65, 2), 256, 0, stream>>>(ub, wff2 + i*131072, 8200, 512, 256, h, nullptr,
                                               ffb2 + i*256, nullptr, nullptr, nullptr);
  }
}

// Round 2
// 726.015 us; speedup vs baseline: 1.4618x; 1.4618x over previous
//
#include <hip/hip_runtime.h>
#include <stdint.h>

// PCT forward: stem(conv1x1+BN+ReLU ×2) -> concat cls -> 4× [LN,QKV,attn,fc,LN,FF]
// B=8 C=256 N=1024 D=256 DK=16 DV=32 H=8 NB=4 P=1025, M_tok=8200

typedef unsigned short u16;
typedef unsigned int   u32;
typedef __bf16 bf16x8 __attribute__((ext_vector_type(8)));
typedef float  f32x4  __attribute__((ext_vector_type(4)));
typedef float  f32x16 __attribute__((ext_vector_type(16)));
typedef u32    u32x4  __attribute__((ext_vector_type(4)));

#define DEV static __device__ __forceinline__

DEV float b2f(u16 h){ u32 u = ((u32)h) << 16; return __builtin_bit_cast(float, u); }
DEV u16 f2b(float f){ u32 u = __builtin_bit_cast(u32, f); u32 r = (u + 0x7fffu + ((u >> 16) & 1u)) >> 16; return (u16)r; }
DEV float gelu_f(float x){ return 0.5f * x * (1.0f + erff(x * 0.7071067811865475f)); }
DEV u32 cvtpk(float lo, float hi){
  u32 w;
  asm("v_cvt_pk_bf16_f32 %0, %1, %2" : "=v"(w) : "v"(lo), "v"(hi));
  return w;
}

typedef void __attribute__((address_space(1)))* gas_t;
typedef void __attribute__((address_space(3)))* las_t;
DEV void cp16(const void* g, void* l){
  __builtin_amdgcn_global_load_lds((gas_t)(uintptr_t)g, (las_t)(uintptr_t)l, 16, 0, 0);
}

// ---------------- weight conversion f32 -> bf16 (with QKV concat) ----------------
struct Seg { const float* src; u16* dst; int n; int period; int dstride; int block0; };
struct SegPack { Seg s[8]; };

__global__ __launch_bounds__(256) void k_convert(SegPack p){
  int bid = blockIdx.x;
  int si = 0;
  #pragma unroll
  for (int i = 1; i < 8; i++) if (bid >= p.s[i].block0) si = i;
  const Seg sg = p.s[si];
  int e0 = (bid - sg.block0) * 2048 + threadIdx.x * 8;
  #pragma unroll
  for (int k = 0; k < 8; k++){
    int e = e0 + k;
    if (e < sg.n) sg.dst[(e / sg.period) * sg.dstride + (e % sg.period)] = f2b(sg.src[e]);
  }
}

// ---------------- x [B,C,N] f32 -> xT [B,N,C] bf16 ----------------
__global__ __launch_bounds__(256) void k_transpose_x(const float* __restrict__ x, u16* __restrict__ xT){
  __shared__ float t[32][33];
  int b = blockIdx.z, ct = blockIdx.y, nt = blockIdx.x;
  int tx = threadIdx.x & 31, ty = threadIdx.x >> 5;  // ty 0..7
  const float* xp = x + ((size_t)b * 256 + ct * 32) * 1024 + nt * 32;
  #pragma unroll
  for (int k = 0; k < 4; k++) t[ty + 8*k][tx] = xp[(size_t)(ty + 8*k) * 1024 + tx];
  __syncthreads();
  u16* op = xT + ((size_t)b * 1024 + nt * 32) * 256 + ct * 32;
  #pragma unroll
  for (int k = 0; k < 4; k++) op[(size_t)(ty + 8*k) * 256 + tx] = f2b(t[tx][ty + 8*k]);
}

// ---------------- cls token row ----------------
__global__ void k_cls(const float* __restrict__ cls, float* __restrict__ h){
  int d = threadIdx.x;
  #pragma unroll
  for (int b = 0; b < 8; b++) h[(size_t)b * 1025 * 256 + d] = cls[d];
}

// ---------------- LayerNorm: h f32 -> y bf16 (wave per token) ----------------
__global__ __launch_bounds__(256) void k_ln(const float* __restrict__ h, const float* __restrict__ g,
                                            const float* __restrict__ bt, u16* __restrict__ y){
  int lane = threadIdx.x & 63, wv = threadIdx.x >> 6;
  long t = (long)blockIdx.x * 4 + wv;
  if (t >= 8200) return;
  const float* row = h + t * 256;
  float4 v = *reinterpret_cast<const float4*>(row + lane * 4);
  float s = v.x + v.y + v.z + v.w;
  float q = v.x*v.x + v.y*v.y + v.z*v.z + v.w*v.w;
  #pragma unroll
  for (int o = 32; o > 0; o >>= 1){ s += __shfl_xor(s, o); q += __shfl_xor(q, o); }
  float mean = s * (1.f/256.f);
  float var  = q * (1.f/256.f) - mean * mean;
  float rs = rsqrtf(var + 1e-5f);
  ushort4 ov;
  const float* vp = &v.x;
  u16* o16 = (u16*)&ov;
  #pragma unroll
  for (int j = 0; j < 4; j++){
    int c = lane * 4 + j;
    o16[j] = f2b((vp[j] - mean) * rs * g[c] + bt[c]);
  }
  *reinterpret_cast<ushort4*>(y + t * 256 + lane * 4) = ov;
}

// ---------------- NT GEMM: out[m,e] = sum_k A[m,k]*W[e,k], bf16 in, f32 acc ----------------
template<int EPI>
__global__ __launch_bounds__(256) void k_gemm(const u16* __restrict__ A, const u16* __restrict__ W,
    int M, int K, int E, float* __restrict__ outF, u16* __restrict__ outB,
    const float* __restrict__ a0, const float* __restrict__ a1,
    const float* __restrict__ a2, const float* __restrict__ a3){
  __shared__ __align__(16) u16 As[8192];
  __shared__ __align__(16) u16 Bs[8192];
  const int tid = threadIdx.x;
  const int lane = tid & 63, wv = tid >> 6;
  const int wr = wv >> 1, wc = wv & 1;
  const int tM = blockIdx.x * 128, tN = blockIdx.y * 128;
  f32x4 acc[4][4];
  #pragma unroll
  for (int m = 0; m < 4; m++)
    #pragma unroll
    for (int n = 0; n < 4; n++)
      #pragma unroll
      for (int j = 0; j < 4; j++) acc[m][n][j] = 0.f;

  const int l8 = lane >> 3, lm = lane & 7;
  for (int k0 = 0; k0 < K; k0 += 64){
    __syncthreads();
    #pragma unroll
    for (int is = 0; is < 4; is++){
      int row = is * 32 + wv * 8 + l8;
      int kg = lm ^ (row & 7);
      int ra = tM + row; ra = ra < M ? ra : M - 1;
      cp16(A + (size_t)ra * K + k0 + kg * 8, As + is * 2048 + wv * 512);
      cp16(W + (size_t)(tN + row) * K + k0 + kg * 8, Bs + is * 2048 + wv * 512);
    }
    __syncthreads();
    #pragma unroll
    for (int kk = 0; kk < 2; kk++){
      bf16x8 af[4], bfv[4];
      #pragma unroll
      for (int m = 0; m < 4; m++){
        int row = wr * 64 + m * 16 + (lane & 15);
        int kg = (kk * 4 + (lane >> 4)) ^ (row & 7);
        af[m] = *reinterpret_cast<const bf16x8*>(&As[row * 64 + kg * 8]);
      }
      #pragma unroll
      for (int n = 0; n < 4; n++){
        int row = wc * 64 + n * 16 + (lane & 15);
        int kg = (kk * 4 + (lane >> 4)) ^ (row & 7);
        bfv[n] = *reinterpret_cast<const bf16x8*>(&Bs[row * 64 + kg * 8]);
      }
      #pragma unroll
      for (int m = 0; m < 4; m++)
        #pragma unroll
        for (int n = 0; n < 4; n++)
          acc[m][n] = __builtin_amdgcn_mfma_f32_16x16x32_bf16(af[m], bfv[n], acc[m][n], 0, 0, 0);
    }
  }
  #pragma unroll
  for (int n = 0; n < 4; n++){
    const int col = tN + wc * 64 + n * 16 + (lane & 15);
    float scale = 0.f, shift = 0.f, bias = 0.f;
    if (EPI == 1 || EPI == 2){
      float gv = a0[col], bv = a1[col], mv = a2[col], vv = a3[col];
      scale = gv * rsqrtf(vv + 1e-5f);
      shift = bv - mv * scale;
    }
    if (EPI == 4 || EPI == 5) bias = a0[col];
    #pragma unroll
    for (int m = 0; m < 4; m++){
      const int row0 = tM + wr * 64 + m * 16 + ((lane >> 4) << 2);
      #pragma unroll
      for (int j = 0; j < 4; j++){
        int r = row0 + j;
        if (r < M){
          float v = acc[m][n][j];
          if (EPI == 0){ outB[(size_t)r * E + col] = f2b(v); }
          else if (EPI == 1){ v = v * scale + shift; v = v > 0.f ? v : 0.f; outB[(size_t)r * E + col] = f2b(v); }
          else if (EPI == 2){ v = v * scale + shift; v = v > 0.f ? v : 0.f; outF[(size_t)(r + (r >> 10) + 1) * 256 + col] = v; }
          else if (EPI == 3){ outF[(size_t)r * E + col] += v; }
          else if (EPI == 4){ outB[(size_t)r * E + col] = f2b(gelu_f(v + bias)); }
          else { outF[(size_t)r * E + col] += v + bias; }
        }
      }
    }
  }
}

// ---------------- attention v2: swapped-QK^T register softmax ----------------
// S^T = mfma(A=K, B=Q^T): lane owns q=col (l32), 16 j-rows in regs.
// PV: O^T = mfma(A=V^T, B=P^T): lane owns q=col, 16 dv-rows. m/ls lane-local.
__global__ __launch_bounds__(256) void k_attn(const u16* __restrict__ qkv,
    const float* __restrict__ pol, u16* __restrict__ o){
  __shared__ __align__(16) u16 vT[32 * 72];        // [dv][64 j + 8 pad]
  __shared__ float pol_s[1088];
  __shared__ float vps[64][33];
  __shared__ float vsum[32];
  const int tid = threadIdx.x;
  const int lane = tid & 63, wv = tid >> 6;
  const int l32 = lane & 31, hi = lane >> 5;
  const int bid = blockIdx.x;
  const int bh = bid / 9, qt = bid - bh * 9;
  const int b = bh >> 3, hh = bh & 7;
  const size_t rowbase = (size_t)b * 1025;
  const int qrow0 = qt * 128 + wv * 32;
  const int qg = qrow0 + l32;                      // this lane's q (unclamped)
  const int qr = qg > 1024 ? 1024 : qg;
  // Q fragment (B operand), pre-scaled by 1/sqrt(DK)=0.25 (exact in bf16)
  bf16x8 qf = *reinterpret_cast<const bf16x8*>(qkv + (rowbase + qr) * 512 + hh * 16 + hi * 8);
  {
    u16* qu = (u16*)&qf;
    #pragma unroll
    for (int j = 0; j < 8; j++) qu[j] = f2b(b2f(qu[j]) * 0.25f);
  }
  for (int t = tid; t < 1088; t += 256) pol_s[t] = (t <= 1024) ? pol[rowbase + t] : 0.f;

  float m = -3.0e38f, ls = 0.f;
  f32x16 oacc;
  #pragma unroll
  for (int r = 0; r < 16; r++) oacc[r] = 0.f;
  float vpart[8] = {0,0,0,0,0,0,0,0};
  const int sj = tid >> 2, sc = tid & 3;

  for (int jt = 0; jt < 17; jt++){
    const int jb = jt * 64;
    __syncthreads();
    { // stage V tile (and accumulate vsum partials)
      int jgs = jb + sj; bool jvld = jgs <= 1024; int jc = jvld ? jgs : 1024;
      bf16x8 vd = *reinterpret_cast<const bf16x8*>(qkv + (rowbase + jc) * 512 + 256 + hh * 32 + sc * 8);
      const u16* vdu = reinterpret_cast<const u16*>(&vd);
      #pragma unroll
      for (int q = 0; q < 8; q++){
        u16 val = jvld ? vdu[q] : (u16)0;
        vT[(sc * 8 + q) * 72 + sj] = val;
        vpart[q] += b2f(val);
      }
    }
    __syncthreads();
    const bool tail = (jb + 63) > 1024;
    #pragma unroll
    for (int sub = 0; sub < 2; sub++){
      const int jb32 = jb + sub * 32;
      int jrow = jb32 + l32; if (jrow > 1024) jrow = 1024;
      const bf16x8 ka = *reinterpret_cast<const bf16x8*>(qkv + (rowbase + jrow) * 512 + 128 + hh * 16 + hi * 8);
      f32x16 fz;
      #pragma unroll
      for (int r = 0; r < 16; r++) fz[r] = 0.f;
      f32x16 st = __builtin_amdgcn_mfma_f32_32x32x16_bf16(ka, qf, fz, 0, 0, 0);
      if (tail){
        #pragma unroll
        for (int r = 0; r < 16; r++){
          int jg2 = jb32 + (r & 3) + 8 * (r >> 2) + 4 * hi;
          if (jg2 > 1024) st[r] = -3.0e38f;
        }
      }
      float mx = st[0];
      #pragma unroll
      for (int r = 1; r < 16; r++) mx = fmaxf(mx, st[r]);
      mx = fmaxf(mx, __shfl_xor(mx, 32));
      const float mn = fmaxf(m, mx);
      const float corr = __expf(m - mn);
      m = mn;
      float e[16];
      float psum = 0.f;
      #pragma unroll
      for (int r = 0; r < 16; r++){
        int jg2 = jb32 + (r & 3) + 8 * (r >> 2) + 4 * hi;
        float pj = pol_s[jg2];
        float ap = (jg2 == qg) ? 1.f : pj;
        float ev = __expf(st[r] - mn) * ap;
        e[r] = ev;
        psum += ev;
      }
      psum += __shfl_xor(psum, 32);
      ls = ls * corr + psum;
      #pragma unroll
      for (int r = 0; r < 16; r++) oacc[r] *= corr;
      // pack P^T (B-operand) and run PV
      #pragma unroll
      for (int c = 0; c < 2; c++){
        u32 A0 = cvtpk(e[c*8+0], e[c*8+1]);
        u32 A1 = cvtpk(e[c*8+2], e[c*8+3]);
        u32 B0 = cvtpk(e[c*8+4], e[c*8+5]);
        u32 B1 = cvtpk(e[c*8+6], e[c*8+7]);
        u32 pA0 = __shfl_xor(A0, 32), pB0 = __shfl_xor(B0, 32);
        u32 pA1 = __shfl_xor(A1, 32), pB1 = __shfl_xor(B1, 32);
        u32x4 pw;
        pw.x = hi ? pB0 : A0;
        pw.y = hi ? pB1 : A1;
        pw.z = hi ? B0 : pA0;
        pw.w = hi ? B1 : pA1;
        bf16x8 pb = __builtin_bit_cast(bf16x8, pw);
        bf16x8 va = *reinterpret_cast<const bf16x8*>(&vT[l32 * 72 + sub * 32 + c * 16 + hi * 8]);
        oacc = __builtin_amdgcn_mfma_f32_32x32x16_bf16(va, pb, oacc, 0, 0, 0);
      }
    }
  }
  __syncthreads();
  #pragma unroll
  for (int q = 0; q < 8; q++) vps[sj][sc * 8 + q] = vpart[q];
  __syncthreads();
  if (tid < 32){
    float s2 = 0.f;
    for (int jj = 0; jj < 64; jj++) s2 += vps[jj][tid];
    vsum[tid] = s2;
  }
  __syncthreads();
  if (qg <= 1024){
    const float inv = 1.f / (ls + 1e-6f);
    const float epsn = 1e-6f / 1025.f;
    u16* orow = o + (rowbase + qg) * 256 + hh * 32;
    #pragma unroll
    for (int rq = 0; rq < 4; rq++){
      const int dv0 = 8 * rq + 4 * hi;
      uint2 wout;
      u32* wp = &wout.x;
      #pragma unroll
      for (int j2 = 0; j2 < 2; j2++){
        float v0 = (oacc[rq*4 + j2*2    ] + epsn * vsum[dv0 + j2*2    ]) * inv;
        float v1 = (oacc[rq*4 + j2*2 + 1] + epsn * vsum[dv0 + j2*2 + 1]) * inv;
        wp[j2] = ((u32)f2b(v1) << 16) | (u32)f2b(v0);
      }
      *reinterpret_cast<uint2*>(orow + dv0) = wout;
    }
  }
}

// ---------------- host ----------------
extern "C" void kernel_launch(void* const* d_in, const int* in_sizes, int n_in,
                              void* d_out, int out_size, void* d_ws, size_t ws_size,
                              hipStream_t stream){
  const float* x    = (const float*)d_in[0];
  const float* pol  = (const float*)d_in[1];
  const float* c1w  = (const float*)d_in[2];
  const float* c2w  = (const float*)d_in[3];
  const float* bn1g = (const float*)d_in[4];
  const float* bn1b = (const float*)d_in[5];
  const float* bn1m = (const float*)d_in[6];
  const float* bn1v = (const float*)d_in[7];
  const float* bn2g = (const float*)d_in[8];
  const float* bn2b = (const float*)d_in[9];
  const float* bn2m = (const float*)d_in[10];
  const float* bn2v = (const float*)d_in[11];
  const float* cls  = (const float*)d_in[12];
  const float* ln1g = (const float*)d_in[13];
  const float* ln1b = (const float*)d_in[14];
  const float* ln2g = (const float*)d_in[15];
  const float* ln2b = (const float*)d_in[16];
  const float* wq   = (const float*)d_in[17];
  const float* wk   = (const float*)d_in[18];
  const float* wvp  = (const float*)d_in[19];
  const float* fcw  = (const float*)d_in[20];
  const float* ffw1 = (const float*)d_in[21];
  const float* ffb1 = (const float*)d_in[22];
  const float* ffw2 = (const float*)d_in[23];
  const float* ffb2 = (const float*)d_in[24];
  float* h = (float*)d_out;

  u16* ws   = (u16*)d_ws;
  u16* wc1  = ws;
  u16* wc2  = wc1  + 65536;
  u16* wqkv = wc2  + 65536;
  u16* wfc  = wqkv + 524288;
  u16* wff1 = wfc  + 262144;
  u16* wff2 = wff1 + 524288;
  u16* xT   = wff2 + 524288;
  u16* h1   = xT   + 2097152;
  u16* yb   = h1   + 2097152;
  u16* qkvb = yb   + 2099200;
  u16* ob   = qkvb + 4198400;
  u16* ub   = qkvb;  // alias: qkv dead after attention

  SegPack sp;
  int b0 = 0;
  sp.s[0] = Seg{ c1w,  wc1,          65536,  65536,  0,      b0 }; b0 += 32;
  sp.s[1] = Seg{ c2w,  wc2,          65536,  65536,  0,      b0 }; b0 += 32;
  sp.s[2] = Seg{ wq,   wqkv,         131072, 32768,  131072, b0 }; b0 += 64;
  sp.s[3] = Seg{ wk,   wqkv + 32768, 131072, 32768,  131072, b0 }; b0 += 64;
  sp.s[4] = Seg{ wvp,  wqkv + 65536, 262144, 65536,  131072, b0 }; b0 += 128;
  sp.s[5] = Seg{ fcw,  wfc,          262144, 262144, 0,      b0 }; b0 += 128;
  sp.s[6] = Seg{ ffw1, wff1,         524288, 524288, 0,      b0 }; b0 += 256;
  sp.s[7] = Seg{ ffw2, wff2,         524288, 524288, 0,      b0 }; b0 += 256;

  k_convert<<<b0, 256, 0, stream>>>(sp);
  k_transpose_x<<<dim3(32, 8, 8), 256, 0, stream>>>(x, xT);
  k_cls<<<1, 256, 0, stream>>>(cls, h);
  k_gemm<1><<<dim3(64, 2), 256, 0, stream>>>(xT, wc1, 8192, 256, 256, nullptr, h1, bn1g, bn1b, bn1m, bn1v);
  k_gemm<2><<<dim3(64, 2), 256, 0, stream>>>(h1, wc2, 8192, 256, 256, h, nullptr, bn2g, bn2b, bn2m, bn2v);
  for (int i = 0; i < 4; i++){
    k_ln<<<2050, 256, 0, stream>>>(h, ln1g + i*256, ln1b + i*256, yb);
    k_gemm<0><<<dim3(65, 4), 256, 0, stream>>>(yb, wqkv + i*131072, 8200, 256, 512, nullptr, qkvb,
                                               nullptr, nullptr, nullptr, nullptr);
    k_attn<<<576, 256, 0, stream>>>(qkvb, pol, ob);
    k_gemm<3><<<dim3(65, 2), 256, 0, stream>>>(ob, wfc + i*65536, 8200, 256, 256, h, nullptr,
                                               nullptr, nullptr, nullptr, nullptr);
    k_ln<<<2050, 256, 0, stream>>>(h, ln2g + i*256, ln2b + i*256, yb);
    k_gemm<4><<<dim3(65, 4), 256, 0, stream>>>(yb, wff1 + i*131072, 8200, 256, 512, nullptr, ub,
                                               ffb1 + i*512, nullptr, nullptr, nullptr);
    k_gemm<5><<<dim3(65, 2), 256, 0, stream>>>(ub, wff2 + i*131072, 8200, 512, 256, h, nullptr,
                                               ffb2 + i*256, nullptr, nullptr, nullptr);
  }
}

// Round 3
// 578.318 us; speedup vs baseline: 1.8351x; 1.2554x over previous
//
#include <hip/hip_runtime.h>
#include <stdint.h>

// PCT forward: stem(conv1x1+BN+ReLU ×2) -> concat cls -> 4× [LN,QKV,attn,fc,LN,FF]
// B=8 C=256 N=1024 D=256 DK=16 DV=32 H=8 NB=4 P=1025, M_tok=8200

typedef unsigned short u16;
typedef unsigned int   u32;
typedef __bf16 bf16x8 __attribute__((ext_vector_type(8)));
typedef float  f32x4  __attribute__((ext_vector_type(4)));
typedef float  f32x16 __attribute__((ext_vector_type(16)));
typedef u32    u32x4  __attribute__((ext_vector_type(4)));

#define DEV static __device__ __forceinline__

DEV float b2f(u16 h){ u32 u = ((u32)h) << 16; return __builtin_bit_cast(float, u); }
DEV u16 f2b(float f){ u32 u = __builtin_bit_cast(u32, f); u32 r = (u + 0x7fffu + ((u >> 16) & 1u)) >> 16; return (u16)r; }
DEV float gelu_f(float x){ return 0.5f * x * (1.0f + erff(x * 0.7071067811865475f)); }
DEV u32 cvtpk(float lo, float hi){
  u32 w;
  asm("v_cvt_pk_bf16_f32 %0, %1, %2" : "=v"(w) : "v"(lo), "v"(hi));
  return w;
}
DEV float exp2_(float x){ float r; asm("v_exp_f32 %0, %1" : "=v"(r) : "v"(x)); return r; }

typedef void __attribute__((address_space(1)))* gas_t;
typedef void __attribute__((address_space(3)))* las_t;
DEV void cp16(const void* g, void* l){
  __builtin_amdgcn_global_load_lds((gas_t)(uintptr_t)g, (las_t)(uintptr_t)l, 16, 0, 0);
}

// ---------------- weight conversion f32 -> bf16 (with QKV concat, optional scale) ----------------
struct Seg { const float* src; u16* dst; int n; int period; int dstride; int block0; float scale; };
struct SegPack { Seg s[8]; };

__global__ __launch_bounds__(256) void k_convert(SegPack p){
  int bid = blockIdx.x;
  int si = 0;
  #pragma unroll
  for (int i = 1; i < 8; i++) if (bid >= p.s[i].block0) si = i;
  const Seg sg = p.s[si];
  int e0 = (bid - sg.block0) * 2048 + threadIdx.x * 8;
  #pragma unroll
  for (int k = 0; k < 8; k++){
    int e = e0 + k;
    if (e < sg.n) sg.dst[(e / sg.period) * sg.dstride + (e % sg.period)] = f2b(sg.src[e] * sg.scale);
  }
}

// ---------------- x [B,C,N] f32 -> xT [B,N,C] bf16 ----------------
__global__ __launch_bounds__(256) void k_transpose_x(const float* __restrict__ x, u16* __restrict__ xT){
  __shared__ float t[32][33];
  int b = blockIdx.z, ct = blockIdx.y, nt = blockIdx.x;
  int tx = threadIdx.x & 31, ty = threadIdx.x >> 5;
  const float* xp = x + ((size_t)b * 256 + ct * 32) * 1024 + nt * 32;
  #pragma unroll
  for (int k = 0; k < 4; k++) t[ty + 8*k][tx] = xp[(size_t)(ty + 8*k) * 1024 + tx];
  __syncthreads();
  u16* op = xT + ((size_t)b * 1024 + nt * 32) * 256 + ct * 32;
  #pragma unroll
  for (int k = 0; k < 4; k++) op[(size_t)(ty + 8*k) * 256 + tx] = f2b(t[tx][ty + 8*k]);
}

// ---------------- cls token row ----------------
__global__ void k_cls(const float* __restrict__ cls, float* __restrict__ h){
  int d = threadIdx.x;
  #pragma unroll
  for (int b = 0; b < 8; b++) h[(size_t)b * 1025 * 256 + d] = cls[d];
}

// ---------------- LayerNorm: h f32 -> y bf16 (wave per token) ----------------
__global__ __launch_bounds__(256) void k_ln(const float* __restrict__ h, const float* __restrict__ g,
                                            const float* __restrict__ bt, u16* __restrict__ y){
  int lane = threadIdx.x & 63, wv = threadIdx.x >> 6;
  long t = (long)blockIdx.x * 4 + wv;
  if (t >= 8200) return;
  const float* row = h + t * 256;
  float4 v = *reinterpret_cast<const float4*>(row + lane * 4);
  float s = v.x + v.y + v.z + v.w;
  float q = v.x*v.x + v.y*v.y + v.z*v.z + v.w*v.w;
  #pragma unroll
  for (int o = 32; o > 0; o >>= 1){ s += __shfl_xor(s, o); q += __shfl_xor(q, o); }
  float mean = s * (1.f/256.f);
  float var  = q * (1.f/256.f) - mean * mean;
  float rs = rsqrtf(var + 1e-5f);
  ushort4 ov;
  const float* vp = &v.x;
  u16* o16 = (u16*)&ov;
  #pragma unroll
  for (int j = 0; j < 4; j++){
    int c = lane * 4 + j;
    o16[j] = f2b((vp[j] - mean) * rs * g[c] + bt[c]);
  }
  *reinterpret_cast<ushort4*>(y + t * 256 + lane * 4) = ov;
}

// ---------------- NT GEMM: out[m,e] = sum_k A[m,k]*W[e,k], bf16 in, f32 acc ----------------
template<int EPI>
__global__ __launch_bounds__(256) void k_gemm(const u16* __restrict__ A, const u16* __restrict__ W,
    int M, int K, int E, float* __restrict__ outF, u16* __restrict__ outB,
    const float* __restrict__ a0, const float* __restrict__ a1,
    const float* __restrict__ a2, const float* __restrict__ a3){
  __shared__ __align__(16) u16 As[8192];
  __shared__ __align__(16) u16 Bs[8192];
  const int tid = threadIdx.x;
  const int lane = tid & 63, wv = tid >> 6;
  const int wr = wv >> 1, wc = wv & 1;
  const int tM = blockIdx.x * 128, tN = blockIdx.y * 128;
  f32x4 acc[4][4];
  #pragma unroll
  for (int m = 0; m < 4; m++)
    #pragma unroll
    for (int n = 0; n < 4; n++)
      #pragma unroll
      for (int j = 0; j < 4; j++) acc[m][n][j] = 0.f;

  const int l8 = lane >> 3, lm = lane & 7;
  for (int k0 = 0; k0 < K; k0 += 64){
    __syncthreads();
    #pragma unroll
    for (int is = 0; is < 4; is++){
      int row = is * 32 + wv * 8 + l8;
      int kg = lm ^ (row & 7);
      int ra = tM + row; ra = ra < M ? ra : M - 1;
      cp16(A + (size_t)ra * K + k0 + kg * 8, As + is * 2048 + wv * 512);
      cp16(W + (size_t)(tN + row) * K + k0 + kg * 8, Bs + is * 2048 + wv * 512);
    }
    __syncthreads();
    #pragma unroll
    for (int kk = 0; kk < 2; kk++){
      bf16x8 af[4], bfv[4];
      #pragma unroll
      for (int m = 0; m < 4; m++){
        int row = wr * 64 + m * 16 + (lane & 15);
        int kg = (kk * 4 + (lane >> 4)) ^ (row & 7);
        af[m] = *reinterpret_cast<const bf16x8*>(&As[row * 64 + kg * 8]);
      }
      #pragma unroll
      for (int n = 0; n < 4; n++){
        int row = wc * 64 + n * 16 + (lane & 15);
        int kg = (kk * 4 + (lane >> 4)) ^ (row & 7);
        bfv[n] = *reinterpret_cast<const bf16x8*>(&Bs[row * 64 + kg * 8]);
      }
      #pragma unroll
      for (int m = 0; m < 4; m++)
        #pragma unroll
        for (int n = 0; n < 4; n++)
          acc[m][n] = __builtin_amdgcn_mfma_f32_16x16x32_bf16(af[m], bfv[n], acc[m][n], 0, 0, 0);
    }
  }
  #pragma unroll
  for (int n = 0; n < 4; n++){
    const int col = tN + wc * 64 + n * 16 + (lane & 15);
    float scale = 0.f, shift = 0.f, bias = 0.f;
    if (EPI == 1 || EPI == 2){
      float gv = a0[col], bv = a1[col], mv = a2[col], vv = a3[col];
      scale = gv * rsqrtf(vv + 1e-5f);
      shift = bv - mv * scale;
    }
    if (EPI == 4 || EPI == 5) bias = a0[col];
    #pragma unroll
    for (int m = 0; m < 4; m++){
      const int row0 = tM + wr * 64 + m * 16 + ((lane >> 4) << 2);
      #pragma unroll
      for (int j = 0; j < 4; j++){
        int r = row0 + j;
        if (r < M){
          float v = acc[m][n][j];
          if (EPI == 0){ outB[(size_t)r * E + col] = f2b(v); }
          else if (EPI == 1){ v = v * scale + shift; v = v > 0.f ? v : 0.f; outB[(size_t)r * E + col] = f2b(v); }
          else if (EPI == 2){ v = v * scale + shift; v = v > 0.f ? v : 0.f; outF[(size_t)(r + (r >> 10) + 1) * 256 + col] = v; }
          else if (EPI == 3){ outF[(size_t)r * E + col] += v; }
          else if (EPI == 4){ outB[(size_t)r * E + col] = f2b(gelu_f(v + bias)); }
          else { outF[(size_t)r * E + col] += v + bias; }
        }
      }
    }
  }
}

// ---------------- attention v3: swapped-QK^T register softmax, in-block j-split ----------------
// 512 threads = 8 waves: waves 0-3 (grp 0) j-tiles 0..8, waves 4-7 (grp 1) tiles 9..16 (+dummy).
// Q pre-scaled by 0.25*log2e (folded into wq conversion) -> exp2 softmax.
// Merge partial (m, ls, O^T) via LDS. eps/n numerator term dropped (~1e-9, << bf16 quantum).
__global__ __launch_bounds__(512) void k_attn(const u16* __restrict__ qkv,
    const float* __restrict__ pol, u16* __restrict__ o){
  __shared__ __align__(16) u16 vT[2][32 * 72];     // per-group [dv][64 j + 8 pad]
  __shared__ float pol_s[1088];
  __shared__ float oB[128][33];
  __shared__ float mB[128], lsB[128];
  const int tid = threadIdx.x;
  const int lane = tid & 63, wv = tid >> 6;
  const int grp = tid >> 8;                        // 0: tiles 0-8, 1: tiles 9-16
  const int wq4 = wv & 3;
  const int l32 = lane & 31, hi = lane >> 5;
  const int bid = blockIdx.x;
  const int bh = bid / 9, qt = bid - bh * 9;
  const int b = bh >> 3, hh = bh & 7;
  const size_t rowbase = (size_t)b * 1025;
  const int qrow0 = qt * 128 + wq4 * 32;
  const int qg = qrow0 + l32;
  const int qr = qg > 1024 ? 1024 : qg;
  const bf16x8 qf = *reinterpret_cast<const bf16x8*>(qkv + (rowbase + qr) * 512 + hh * 16 + hi * 8);
  for (int t = tid; t < 1088; t += 512) pol_s[t] = (t <= 1024) ? pol[rowbase + t] : 0.f;

  float m = -3.0e38f, ls = 0.f;
  f32x16 oacc;
  #pragma unroll
  for (int r = 0; r < 16; r++) oacc[r] = 0.f;
  const int gt = tid & 255, sj = gt >> 2, sc = gt & 3;

  for (int it = 0; it < 9; it++){
    const int jt = grp == 0 ? it : 9 + it;         // grp1 it=8 -> jt=17 (dummy, fully masked)
    const int jb = jt * 64;
    __syncthreads();
    { // stage this group's V tile
      int jgs = jb + sj; bool jvld = jgs <= 1024; int jc = jvld ? jgs : 1024;
      bf16x8 vd = *reinterpret_cast<const bf16x8*>(qkv + (rowbase + jc) * 512 + 256 + hh * 32 + sc * 8);
      const u16* vdu = reinterpret_cast<const u16*>(&vd);
      #pragma unroll
      for (int q = 0; q < 8; q++) vT[grp][(sc * 8 + q) * 72 + sj] = jvld ? vdu[q] : (u16)0;
    }
    __syncthreads();
    const bool tail = (jb + 63) > 1024;
    #pragma unroll
    for (int sub = 0; sub < 2; sub++){
      const int jb32 = jb + sub * 32;
      int jrow = jb32 + l32; if (jrow > 1024) jrow = 1024;
      const bf16x8 ka = *reinterpret_cast<const bf16x8*>(qkv + (rowbase + jrow) * 512 + 128 + hh * 16 + hi * 8);
      f32x16 fz;
      #pragma unroll
      for (int r = 0; r < 16; r++) fz[r] = 0.f;
      f32x16 st = __builtin_amdgcn_mfma_f32_32x32x16_bf16(ka, qf, fz, 0, 0, 0);
      if (tail){
        #pragma unroll
        for (int r = 0; r < 16; r++){
          int jg2 = jb32 + (r & 3) + 8 * (r >> 2) + 4 * hi;
          if (jg2 > 1024) st[r] = -3.0e38f;
        }
      }
      float mx = st[0];
      #pragma unroll
      for (int r = 1; r < 16; r++) mx = fmaxf(mx, st[r]);
      mx = fmaxf(mx, __shfl_xor(mx, 32));
      const float mn = fmaxf(m, mx);
      const float corr = exp2_(m - mn);
      m = mn;
      float e[16];
      float psum = 0.f;
      #pragma unroll
      for (int r = 0; r < 16; r++){
        int jg2 = jb32 + (r & 3) + 8 * (r >> 2) + 4 * hi;
        float pj = pol_s[jg2];
        float ap = (jg2 == qg) ? 1.f : pj;
        float ev = exp2_(st[r] - mn) * ap;
        e[r] = ev;
        psum += ev;
      }
      psum += __shfl_xor(psum, 32);
      ls = ls * corr + psum;
      #pragma unroll
      for (int r = 0; r < 16; r++) oacc[r] *= corr;
      #pragma unroll
      for (int c = 0; c < 2; c++){
        u32 A0 = cvtpk(e[c*8+0], e[c*8+1]);
        u32 A1 = cvtpk(e[c*8+2], e[c*8+3]);
        u32 B0 = cvtpk(e[c*8+4], e[c*8+5]);
        u32 B1 = cvtpk(e[c*8+6], e[c*8+7]);
        u32 pA0 = __shfl_xor(A0, 32), pB0 = __shfl_xor(B0, 32);
        u32 pA1 = __shfl_xor(A1, 32), pB1 = __shfl_xor(B1, 32);
        u32x4 pw;
        pw.x = hi ? pB0 : A0;
        pw.y = hi ? pB1 : A1;
        pw.z = hi ? B0 : pA0;
        pw.w = hi ? B1 : pA1;
        bf16x8 pb = __builtin_bit_cast(bf16x8, pw);
        bf16x8 va = *reinterpret_cast<const bf16x8*>(&vT[grp][l32 * 72 + sub * 32 + c * 16 + hi * 8]);
        oacc = __builtin_amdgcn_mfma_f32_32x32x16_bf16(va, pb, oacc, 0, 0, 0);
      }
    }
  }
  __syncthreads();
  const int qi = wq4 * 32 + l32;
  if (grp == 1){
    mB[qi] = m; lsB[qi] = ls;
    #pragma unroll
    for (int r = 0; r < 16; r++) oB[qi][(r & 3) + 8 * (r >> 2) + 4 * hi] = oacc[r];
  }
  __syncthreads();
  if (grp == 0 && qg <= 1024){
    const float mb = mB[qi], lb = lsB[qi];
    const float mt = fmaxf(m, mb);
    const float cA = exp2_(m - mt), cB = exp2_(mb - mt);
    const float inv = 1.f / (ls * cA + lb * cB + 1e-6f);
    u16* orow = o + (rowbase + qg) * 256 + hh * 32;
    #pragma unroll
    for (int rq = 0; rq < 4; rq++){
      const int dv0 = 8 * rq + 4 * hi;
      uint2 wout;
      u32* wp = &wout.x;
      #pragma unroll
      for (int j2 = 0; j2 < 2; j2++){
        float v0 = (oacc[rq*4 + j2*2    ] * cA + oB[qi][dv0 + j2*2    ] * cB) * inv;
        float v1 = (oacc[rq*4 + j2*2 + 1] * cA + oB[qi][dv0 + j2*2 + 1] * cB) * inv;
        wp[j2] = ((u32)f2b(v1) << 16) | (u32)f2b(v0);
      }
      *reinterpret_cast<uint2*>(orow + dv0) = wout;
    }
  }
}

// ---------------- host ----------------
extern "C" void kernel_launch(void* const* d_in, const int* in_sizes, int n_in,
                              void* d_out, int out_size, void* d_ws, size_t ws_size,
                              hipStream_t stream){
  const float* x    = (const float*)d_in[0];
  const float* pol  = (const float*)d_in[1];
  const float* c1w  = (const float*)d_in[2];
  const float* c2w  = (const float*)d_in[3];
  const float* bn1g = (const float*)d_in[4];
  const float* bn1b = (const float*)d_in[5];
  const float* bn1m = (const float*)d_in[6];
  const float* bn1v = (const float*)d_in[7];
  const float* bn2g = (const float*)d_in[8];
  const float* bn2b = (const float*)d_in[9];
  const float* bn2m = (const float*)d_in[10];
  const float* bn2v = (const float*)d_in[11];
  const float* cls  = (const float*)d_in[12];
  const float* ln1g = (const float*)d_in[13];
  const float* ln1b = (const float*)d_in[14];
  const float* ln2g = (const float*)d_in[15];
  const float* ln2b = (const float*)d_in[16];
  const float* wq   = (const float*)d_in[17];
  const float* wk   = (const float*)d_in[18];
  const float* wvp  = (const float*)d_in[19];
  const float* fcw  = (const float*)d_in[20];
  const float* ffw1 = (const float*)d_in[21];
  const float* ffb1 = (const float*)d_in[22];
  const float* ffw2 = (const float*)d_in[23];
  const float* ffb2 = (const float*)d_in[24];
  float* h = (float*)d_out;

  u16* ws   = (u16*)d_ws;
  u16* wc1  = ws;
  u16* wc2  = wc1  + 65536;
  u16* wqkv = wc2  + 65536;
  u16* wfc  = wqkv + 524288;
  u16* wff1 = wfc  + 262144;
  u16* wff2 = wff1 + 524288;
  u16* xT   = wff2 + 524288;
  u16* h1   = xT   + 2097152;
  u16* yb   = h1   + 2097152;
  u16* qkvb = yb   + 2099200;
  u16* ob   = qkvb + 4198400;
  u16* ub   = qkvb;  // alias: qkv dead after attention

  const float QSCALE = 0.25f * 1.4426950408889634f;  // 1/sqrt(DK) * log2(e), folded into wq
  SegPack sp;
  int b0 = 0;
  sp.s[0] = Seg{ c1w,  wc1,          65536,  65536,  0,      b0, 1.f }; b0 += 32;
  sp.s[1] = Seg{ c2w,  wc2,          65536,  65536,  0,      b0, 1.f }; b0 += 32;
  sp.s[2] = Seg{ wq,   wqkv,         131072, 32768,  131072, b0, QSCALE }; b0 += 64;
  sp.s[3] = Seg{ wk,   wqkv + 32768, 131072, 32768,  131072, b0, 1.f }; b0 += 64;
  sp.s[4] = Seg{ wvp,  wqkv + 65536, 262144, 65536,  131072, b0, 1.f }; b0 += 128;
  sp.s[5] = Seg{ fcw,  wfc,          262144, 262144, 0,      b0, 1.f }; b0 += 128;
  sp.s[6] = Seg{ ffw1, wff1,         524288, 524288, 0,      b0, 1.f }; b0 += 256;
  sp.s[7] = Seg{ ffw2, wff2,         524288, 524288, 0,      b0, 1.f }; b0 += 256;

  k_convert<<<b0, 256, 0, stream>>>(sp);
  k_transpose_x<<<dim3(32, 8, 8), 256, 0, stream>>>(x, xT);
  k_cls<<<1, 256, 0, stream>>>(cls, h);
  k_gemm<1><<<dim3(64, 2), 256, 0, stream>>>(xT, wc1, 8192, 256, 256, nullptr, h1, bn1g, bn1b, bn1m, bn1v);
  k_gemm<2><<<dim3(64, 2), 256, 0, stream>>>(h1, wc2, 8192, 256, 256, h, nullptr, bn2g, bn2b, bn2m, bn2v);
  for (int i = 0; i < 4; i++){
    k_ln<<<2050, 256, 0, stream>>>(h, ln1g + i*256, ln1b + i*256, yb);
    k_gemm<0><<<dim3(65, 4), 256, 0, stream>>>(yb, wqkv + i*131072, 8200, 256, 512, nullptr, qkvb,
                                               nullptr, nullptr, nullptr, nullptr);
    k_attn<<<576, 512, 0, stream>>>(qkvb, pol, ob);
    k_gemm<3><<<dim3(65, 2), 256, 0, stream>>>(ob, wfc + i*65536, 8200, 256, 256, h, nullptr,
                                               nullptr, nullptr, nullptr, nullptr);
    k_ln<<<2050, 256, 0, stream>>>(h, ln2g + i*256, ln2b + i*256, yb);
    k_gemm<4><<<dim3(65, 4), 256, 0, stream>>>(yb, wff1 + i*131072, 8200, 256, 512, nullptr, ub,
                                               ffb1 + i*512, nullptr, nullptr, nullptr);
    k_gemm<5><<<dim3(65, 2), 256, 0, stream>>>(ub, wff2 + i*131072, 8200, 512, 256, h, nullptr,
                                               ffb2 + i*256, nullptr, nullptr, nullptr);
  }
}